// Round 10
// baseline (133.034 us; speedup 1.0000x reference)
//
#include <hip/hip_runtime.h>
#include <hip/hip_bf16.h>
#include <stdint.h>

#define N_TOTAL 8192
#define HALF_N  4096
#define DIM     512
#define INV_TAU (1.0f/0.07f)

typedef __attribute__((ext_vector_type(8))) short short8;
typedef __attribute__((ext_vector_type(4))) float f32x4;

#define AS1 __attribute__((address_space(1)))
#define AS3 __attribute__((address_space(3)))

__device__ __forceinline__ uint32_t umax32(uint32_t a, uint32_t b) { return a > b ? a : b; }
__device__ __forceinline__ uint32_t umin32(uint32_t a, uint32_t b) { return a < b ? a : b; }

__device__ __forceinline__ float decode_key(uint32_t key)
{
    ushort h = (key & 0x8000u) ? (ushort)(key ^ 0x8000u) : (ushort)(key ^ 0xFFFFu);
    return (float)(*(_Float16*)&h);
}

// ---------------- Kernel 0: row-normalize, emit bf16 z ----------------
__global__ __launch_bounds__(256) void norm_kernel(const float* __restrict__ z1,
                                                   const float* __restrict__ z2,
                                                   ushort* __restrict__ zb)
{
    int row  = blockIdx.x * 4 + (threadIdx.x >> 6);
    int lane = threadIdx.x & 63;
    const float* src = (row < HALF_N) ? (z1 + (size_t)row * DIM)
                                      : (z2 + (size_t)(row - HALF_N) * DIM);
    const float4* p = (const float4*)src;
    float4 a = p[lane * 2];
    float4 b = p[lane * 2 + 1];
    float ss = a.x*a.x + a.y*a.y + a.z*a.z + a.w*a.w
             + b.x*b.x + b.y*b.y + b.z*b.z + b.w*b.w;
#pragma unroll
    for (int o = 1; o < 64; o <<= 1) ss += __shfl_xor(ss, o);
    float sc = 1.0f / fmaxf(sqrtf(ss), 1e-12f);

    float v[8] = {a.x*sc, a.y*sc, a.z*sc, a.w*sc, b.x*sc, b.y*sc, b.z*sc, b.w*sc};
    alignas(16) ushort u[8];
#pragma unroll
    for (int j = 0; j < 8; j++) {
        __hip_bfloat16 h = __float2bfloat16(v[j]);
        u[j] = *(ushort*)&h;
    }
    *(uint4*)(zb + (size_t)row * DIM + lane * 8) = *(const uint4*)u;
}

// ---------------- Kernel 1: upper-triangle 256x256 bf16 MFMA GEMM -----
// 8-phase schedule at BK=64: per K-tile 4 phases (one C-quadrant each,
// 16 MFMA), ds_read || stage-issue -> barrier -> lgkmcnt(0) -> setprio(1)
// MFMA setprio(0) -> barrier. Stage kt+1's A at phase 1, B at phase 2,
// into buf^1 (WAR-safe); boundary vmcnt(0) lands 2-3 phases after issue.
// LDS 128 KB (2 x (A 32K + B 32K)), XOR-swizzle s = c ^ (row&7), realized
// via pre-swizzled global source (global_load_lds writes linearly).
__global__ __launch_bounds__(512, 2) void gemm_kernel(const ushort* __restrict__ zb,
                                                      float* __restrict__ rowsum,
                                                      uint2* __restrict__ partial,
                                                      float* __restrict__ pos_sim)
{
    // XCD-aware swizzle: 528 = 8 * 66, bijective
    int orig = blockIdx.x;
    int bid  = (orig & 7) * 66 + (orig >> 3);

    // triangular decode: bid -> (by, bx), bx >= by, 32-wide upper triangle
    int by = (int)(32.5f - sqrtf(1056.25f - 2.0f * (float)bid));
    int off = 32 * by - (by * (by - 1)) / 2;
    if (off > bid) { --by; off = 32 * by - (by * (by - 1)) / 2; }
    else {
        int offn = 32 * (by + 1) - ((by + 1) * by) / 2;
        if (offn <= bid) { ++by; off = offn; }
    }
    int bx = by + (bid - off);

    const int brow = by * 256;
    const int bcol = bx * 256;

    __shared__ ushort As[2][256 * 64];   // 32 KB per buffer
    __shared__ ushort Bs[2][256 * 64];   // total 128 KB

    const int t    = threadIdx.x;
    const int w    = t >> 6;
    const int lane = t & 63;
    const int wr   = w >> 2, wc = w & 3;       // 2x4 waves of 128x64

    f32x4 acc[8][4] = {};

    // staging: unit u = j*512 + t -> LDS slot (row=u>>3, s=u&7); source
    // fetches logical chunk q = s ^ (row&7)  (involution, kt-independent)
    const int srow = t >> 3;                               // 0..63
    const int sq   = ((t & 7) ^ (srow & 7)) * 8;           // elem offset

#define STAGE_A(buf, kt) do {                                                      \
    _Pragma("unroll") for (int j = 0; j < 4; j++)                                  \
        __builtin_amdgcn_global_load_lds(                                          \
            (const AS1 uint32_t*)(zb + (size_t)(brow + j*64 + srow) * DIM + (kt)*64 + sq), \
            (AS3 uint32_t*)((char*)As[buf] + (j*512 + w*64)*16), 16, 0, 0);        \
} while (0)
#define STAGE_B(buf, kt) do {                                                      \
    _Pragma("unroll") for (int j = 0; j < 4; j++)                                  \
        __builtin_amdgcn_global_load_lds(                                          \
            (const AS1 uint32_t*)(zb + (size_t)(bcol + j*64 + srow) * DIM + (kt)*64 + sq), \
            (AS3 uint32_t*)((char*)Bs[buf] + (j*512 + w*64)*16), 16, 0, 0);        \
} while (0)

// one phase: quadrant (MH,NH) of the current K-tile in buf `cur`
#define PHASE(MH, NH, STAGECODE, BOUNDARY) do {                                    \
    short8 av[4][2], bv[2][2];                                                     \
    _Pragma("unroll") for (int m4 = 0; m4 < 4; m4++)                               \
        _Pragma("unroll") for (int kk = 0; kk < 2; kk++) {                         \
            int ro = wr*128 + ((MH)*4 + m4)*16 + (lane & 15);                      \
            int c  = kk*4 + (lane >> 4);                                           \
            av[m4][kk] = *(const short8*)((const char*)As[cur] +                   \
                          (ro*8 + (c ^ (ro & 7)))*16);                             \
        }                                                                          \
    _Pragma("unroll") for (int n2 = 0; n2 < 2; n2++)                               \
        _Pragma("unroll") for (int kk = 0; kk < 2; kk++) {                         \
            int ro = wc*64 + ((NH)*2 + n2)*16 + (lane & 15);                       \
            int c  = kk*4 + (lane >> 4);                                           \
            bv[n2][kk] = *(const short8*)((const char*)Bs[cur] +                   \
                          (ro*8 + (c ^ (ro & 7)))*16);                             \
        }                                                                          \
    STAGECODE;                                                                     \
    __builtin_amdgcn_s_barrier();                                                  \
    asm volatile("s_waitcnt lgkmcnt(0)" ::: "memory");                             \
    __builtin_amdgcn_sched_barrier(0);                                             \
    __builtin_amdgcn_s_setprio(1);                                                 \
    _Pragma("unroll") for (int m4 = 0; m4 < 4; m4++)                               \
        _Pragma("unroll") for (int n2 = 0; n2 < 2; n2++)                           \
            _Pragma("unroll") for (int kk = 0; kk < 2; kk++)                       \
                acc[(MH)*4+m4][(NH)*2+n2] = __builtin_amdgcn_mfma_f32_16x16x32_bf16( \
                    av[m4][kk], bv[n2][kk], acc[(MH)*4+m4][(NH)*2+n2], 0, 0, 0);   \
    __builtin_amdgcn_s_setprio(0);                                                 \
    if (BOUNDARY) asm volatile("s_waitcnt vmcnt(0)" ::: "memory");                 \
    __builtin_amdgcn_s_barrier();                                                  \
} while (0)

    // prologue: stage K-tile 0 fully, drain, publish
    STAGE_A(0, 0);
    STAGE_B(0, 0);
    asm volatile("s_waitcnt vmcnt(0)" ::: "memory");
    __builtin_amdgcn_s_barrier();

    int cur = 0;
    for (int kt = 0; kt < DIM / 64; ++kt) {
        const bool pf = (kt + 1 < DIM / 64);
        PHASE(0, 0, if (pf) STAGE_A(cur ^ 1, kt + 1), false);
        PHASE(1, 0, if (pf) STAGE_B(cur ^ 1, kt + 1), false);
        PHASE(1, 1, , false);
        PHASE(0, 1, , true);     // boundary: vmcnt(0) ~2-3 phases after issue
        cur ^= 1;
    }
#undef PHASE
#undef STAGE_A
#undef STAGE_B

    // cross: by < 16 <= bx (first-half rows, second-half cols)
    const bool is_cross = (brow < HALF_N) && (bcol >= HALF_N);
    const bool off_diag = (bx != by);

    float    cs[4] = {0.f, 0.f, 0.f, 0.f};          // col-side exp sums
    uint32_t s1[4] = {0u, 0u, 0u, 0u};              // col-side top-2
    uint32_t s2[4] = {0u, 0u, 0u, 0u};

    // ---- single fused epilogue pass (verified in R9, absmax 0.0) ----
#pragma unroll
    for (int m = 0; m < 8; m++) {
#pragma unroll
        for (int r = 0; r < 4; r++) {
            int grow = brow + wr * 128 + m * 16 + ((lane >> 4) << 2) + r;
            float rs = 0.f;
            uint32_t t1 = 0u, t2 = 0u;
#pragma unroll
            for (int n = 0; n < 4; n++) {
                int gcol = bcol + wc * 64 + n * 16 + (lane & 15);
                float v  = acc[m][n][r];
                float e  = (grow == gcol) ? 0.f : __expf(v * INV_TAU);
                rs += e;
                cs[n] += e;
                if (is_cross) {
                    int cidx = gcol - HALF_N;
                    ushort h;
                    *(_Float16*)&h = (_Float16)v;
                    uint32_t key = ((uint32_t)(ushort)(h ^ (ushort)((ushort)((short)h >> 15) | 0x8000))) << 16;
                    uint32_t xr = key | (uint32_t)(4095 - cidx);   // row-side: col index
                    uint32_t mn = umin32(t1, xr);
                    t1 = umax32(t1, xr);
                    t2 = umax32(t2, mn);
                    uint32_t xc = key | (uint32_t)(4095 - grow);   // col-side: row index
                    mn = umin32(s1[n], xc);
                    s1[n] = umax32(s1[n], xc);
                    s2[n] = umax32(s2[n], mn);
                    if (cidx == grow) { pos_sim[grow] = v; pos_sim[gcol] = v; }
                }
            }
            rs += __shfl_xor(rs, 1);
            rs += __shfl_xor(rs, 2);
            rs += __shfl_xor(rs, 4);
            rs += __shfl_xor(rs, 8);
            if ((lane & 15) == 0) atomicAdd(&rowsum[grow], rs);

            if (is_cross) {
#pragma unroll
                for (int o = 1; o < 16; o <<= 1) {
                    uint32_t o1 = __shfl_xor(t1, o);
                    uint32_t o2 = __shfl_xor(t2, o);
                    uint32_t nt2 = umax32(umin32(t1, o1), umax32(t2, o2));
                    t1 = umax32(t1, o1);
                    t2 = nt2;
                }
                if ((lane & 15) == 0)
                    partial[((size_t)grow << 6) + (bx - 16) * 4 + wc] = make_uint2(t1, t2);
            }
        }
    }

    // ---- col-side finalize (reduce over lane bits 4,5 = row groups) ----
    if (off_diag) {
#pragma unroll
        for (int n = 0; n < 4; n++) {
            float c = cs[n];
            c += __shfl_xor(c, 16);
            c += __shfl_xor(c, 32);
            uint32_t a1 = s1[n], a2 = s2[n];
            if (is_cross) {
#pragma unroll
                for (int o = 16; o < 64; o <<= 1) {
                    uint32_t o1 = __shfl_xor(a1, o);
                    uint32_t o2 = __shfl_xor(a2, o);
                    uint32_t nt2 = umax32(umin32(a1, o1), umax32(a2, o2));
                    a1 = umax32(a1, o1);
                    a2 = nt2;
                }
            }
            if (lane < 16) {
                int gcol = bcol + wc * 64 + n * 16 + lane;
                atomicAdd(&rowsum[gcol], c);
                if (is_cross)
                    partial[((size_t)gcol << 6) + by * 2 + wr] = make_uint2(a1, a2);
            }
        }
    }
}

// ---------------- Kernel 2: per-row top-10 + per-row loss --------------
// 64 slots/row; second-half rows have 32 real + 32 zero slots (memset);
// packed 0 can never win (any real key >= key(-1) = 0x43FF0000).
__global__ __launch_bounds__(256) void topk_loss_kernel(const uint2* __restrict__ partial,
                                                        const float* __restrict__ pos_sim,
                                                        const float* __restrict__ rowsum,
                                                        float* __restrict__ contrib)
{
    int i    = blockIdx.x * 4 + (threadIdx.x >> 6);
    int lane = threadIdx.x & 63;

    uint2 p = partial[((size_t)i << 6) + lane];
    uint32_t t1 = p.x, t2 = p.y;

    int posidx = i & (HALF_N - 1);
    float S10 = 0.f; int posflag = 0;
#pragma unroll
    for (int tc = 0; tc < 10; tc++) {
        uint32_t b = umax32(t1, t2);
#pragma unroll
        for (int o = 32; o; o >>= 1)
            b = umax32(b, __shfl_xor(b, o));
        bool w1 = (b == t1);
        bool w2 = (b == t2);
        t1 = w1 ? t2 : t1;
        t2 = (w1 | w2) ? 0u : t2;

        int idx = 4095 - (int)(b & 0xFFFFu);
        S10 += decode_key(b >> 16);
        posflag |= (idx == posidx) ? 1 : 0;
    }

    if (lane == 0) {
        float ps  = pos_sim[i];
        float lse = logf(rowsum[i]);
        float L   = 1.0f + 0.75f * (10 - posflag);
        float sll = INV_TAU * (ps + 0.75f * (S10 - posflag * ps));
        contrib[i] = L * lse - sll;
    }
}

// ---------------- Kernel 3: deterministic final reduce -----------------
__global__ __launch_bounds__(256) void reduce_kernel(const float* __restrict__ contrib,
                                                     float* __restrict__ out)
{
    int t = threadIdx.x;
    float s = 0.f;
    for (int j = t; j < N_TOTAL; j += 256) s += contrib[j];
#pragma unroll
    for (int o = 1; o < 64; o <<= 1) s += __shfl_xor(s, o);
    __shared__ float wsum[4];
    if ((t & 63) == 0) wsum[t >> 6] = s;
    __syncthreads();
    if (t == 0) out[0] = (wsum[0] + wsum[1] + wsum[2] + wsum[3]) * (1.0f / N_TOTAL);
}

extern "C" void kernel_launch(void* const* d_in, const int* in_sizes, int n_in,
                              void* d_out, int out_size, void* d_ws, size_t ws_size,
                              hipStream_t stream)
{
    const float* z1 = (const float*)d_in[0];
    const float* z2 = (const float*)d_in[1];
    float* out = (float*)d_out;

    char* ws = (char*)d_ws;
    ushort* zb      = (ushort*)ws;                     //  8 MB   8192x512 bf16
    float*  rowsum  = (float*)(ws + 8388608);          // 32 KB
    float*  pos_sim = (float*)(ws + 8421376);          // 32 KB
    uint2*  partial = (uint2*)(ws + 8454144);          //  4 MB   8192x64 uint2
    float*  contrib = (float*)(ws + 12648448);         // 32 KB

    hipMemsetAsync(rowsum, 0, N_TOTAL * sizeof(float), stream);
    hipMemsetAsync(partial, 0, N_TOTAL * 64 * sizeof(uint2), stream);

    norm_kernel<<<N_TOTAL / 4, 256, 0, stream>>>(z1, z2, zb);
    gemm_kernel<<<528, 512, 0, stream>>>(zb, rowsum, partial, pos_sim);
    topk_loss_kernel<<<N_TOTAL / 4, 256, 0, stream>>>(partial, pos_sim, rowsum, contrib);
    reduce_kernel<<<1, 256, 0, stream>>>(contrib, out);
}

// Round 11
// 108.100 us; speedup vs baseline: 1.2307x; 1.2307x over previous
//
#include <hip/hip_runtime.h>
#include <hip/hip_bf16.h>
#include <stdint.h>

#define N_TOTAL 8192
#define HALF_N  4096
#define DIM     512
#define INV_TAU (1.0f/0.07f)

typedef __attribute__((ext_vector_type(8))) short short8;
typedef __attribute__((ext_vector_type(4))) float f32x4;

#define AS1 __attribute__((address_space(1)))
#define AS3 __attribute__((address_space(3)))

__device__ __forceinline__ uint32_t umax32(uint32_t a, uint32_t b) { return a > b ? a : b; }
__device__ __forceinline__ uint32_t umin32(uint32_t a, uint32_t b) { return a < b ? a : b; }

__device__ __forceinline__ float decode_key(uint32_t key)
{
    ushort h = (key & 0x8000u) ? (ushort)(key ^ 0x8000u) : (ushort)(key ^ 0xFFFFu);
    return (float)(*(_Float16*)&h);
}

// ---------------- Kernel 0: row-normalize, emit bf16 z; zero rowsum ----
__global__ __launch_bounds__(256) void norm_kernel(const float* __restrict__ z1,
                                                   const float* __restrict__ z2,
                                                   ushort* __restrict__ zb,
                                                   float* __restrict__ rowsum)
{
    if (threadIdx.x < 4) rowsum[blockIdx.x * 4 + threadIdx.x] = 0.f;

    int row  = blockIdx.x * 4 + (threadIdx.x >> 6);
    int lane = threadIdx.x & 63;
    const float* src = (row < HALF_N) ? (z1 + (size_t)row * DIM)
                                      : (z2 + (size_t)(row - HALF_N) * DIM);
    const float4* p = (const float4*)src;
    float4 a = p[lane * 2];
    float4 b = p[lane * 2 + 1];
    float ss = a.x*a.x + a.y*a.y + a.z*a.z + a.w*a.w
             + b.x*b.x + b.y*b.y + b.z*b.z + b.w*b.w;
#pragma unroll
    for (int o = 1; o < 64; o <<= 1) ss += __shfl_xor(ss, o);
    float sc = 1.0f / fmaxf(sqrtf(ss), 1e-12f);

    float v[8] = {a.x*sc, a.y*sc, a.z*sc, a.w*sc, b.x*sc, b.y*sc, b.z*sc, b.w*sc};
    alignas(16) ushort u[8];
#pragma unroll
    for (int j = 0; j < 8; j++) {
        __hip_bfloat16 h = __float2bfloat16(v[j]);
        u[j] = *(ushort*)&h;
    }
    *(uint4*)(zb + (size_t)row * DIM + lane * 8) = *(const uint4*)u;
}

// ---------------- Kernel 1: 256x128-tile triangular bf16 MFMA GEMM ----
// Row-pair triangle: by2 in 0..31, bx in 2*by2..63 (1056 blocks = 8*132,
// XCD-swizzled). 4 waves (2 row-groups x 2 col-groups), per-wave 128x64
// output = acc[8][4] (R9-verified mapping). R7's proven 2-phase loop,
// BK=32, pre-swizzled-source gload_lds. 128 MFMA per barrier (2x R7) at
// 48 KB LDS -> the vmcnt(0)+barrier drain amortizes over 2x compute.
// Wave-level triangle flags: old_by = 2*by2+wr; row_act = bx>=old_by,
// col_act = bx>old_by (redundant wr-half on bx==2*by2 blocks: ~1.5% FLOP).
__global__ __launch_bounds__(256, 3) void gemm_kernel(const ushort* __restrict__ zb,
                                                      float* __restrict__ rowsum,
                                                      uint2* __restrict__ partial,
                                                      float* __restrict__ pos_sim)
{
    // XCD-aware swizzle: 1056 = 8 * 132, bijective
    int orig = blockIdx.x;
    int bid  = (orig & 7) * 132 + (orig >> 3);

    // decode bid -> (by2, bx): off(by2) = by2*(65-by2)
    int by2 = (int)(32.5f - sqrtf(1056.25f - (float)bid));
    int off = by2 * (65 - by2);
    if (off > bid) { --by2; off = by2 * (65 - by2); }
    else {
        int offn = (by2 + 1) * (64 - by2);
        if (offn <= bid) { ++by2; off = offn; }
    }
    int bx = 2 * by2 + (bid - off);

    const int brow = by2 * 256;
    const int bcol = bx * 128;

    __shared__ ushort As[2][256 * 32];   // 16 KB per buffer
    __shared__ ushort Bs[2][128 * 32];   //  8 KB per buffer -> 48 KB total

    const int t    = threadIdx.x;
    const int w    = t >> 6;
    const int lane = t & 63;
    const int wr   = w >> 1, wc = w & 1;       // 2x2 waves; wave = 128 rows x 64 cols

    f32x4 acc[8][4] = {};

    // staging: unit u = j*256+t -> LDS slot (row=u>>2, s=u&3); source chunk
    // q = s ^ ((row>>1)&3); with u=j*256+t: row = j*64+(t>>2), q j-indep.
    const int rowt = t >> 2;
    const int qoff = ((t & 3) ^ ((t >> 3) & 3)) * 8;
    const size_t gaA = (size_t)(brow + rowt) * DIM + qoff;
    const size_t gaB = (size_t)(bcol + rowt) * DIM + qoff;

#define STAGE(buf, ko) do {                                                        \
    _Pragma("unroll") for (int j = 0; j < 4; j++)                                  \
        __builtin_amdgcn_global_load_lds(                                          \
            (const AS1 uint32_t*)(zb + gaA + (size_t)j * 64 * DIM + (ko)),         \
            (AS3 uint32_t*)((char*)As[buf] + (j*256 + w*64)*16), 16, 0, 0);        \
    _Pragma("unroll") for (int j = 0; j < 2; j++)                                  \
        __builtin_amdgcn_global_load_lds(                                          \
            (const AS1 uint32_t*)(zb + gaB + (size_t)j * 64 * DIM + (ko)),         \
            (AS3 uint32_t*)((char*)Bs[buf] + (j*256 + w*64)*16), 16, 0, 0);        \
} while (0)

    STAGE(0, 0);
    __syncthreads();

    int cur = 0;
    for (int kt = 0; kt < DIM / 32; ++kt) {
        if (kt + 1 < DIM / 32) STAGE(cur ^ 1, (kt + 1) * 32);

        short8 av[8], bv[4];
#pragma unroll
        for (int m = 0; m < 8; m++) {
            int ro = wr * 128 + m * 16 + (lane & 15);
            int s  = (lane >> 4) ^ ((ro >> 1) & 3);
            av[m] = *(const short8*)((const char*)As[cur] + (ro * 4 + s) * 16);
        }
#pragma unroll
        for (int n = 0; n < 4; n++) {
            int ro = wc * 64 + n * 16 + (lane & 15);
            int s  = (lane >> 4) ^ ((ro >> 1) & 3);
            bv[n] = *(const short8*)((const char*)Bs[cur] + (ro * 4 + s) * 16);
        }
#pragma unroll
        for (int m = 0; m < 8; m++)
#pragma unroll
            for (int n = 0; n < 4; n++)
                acc[m][n] = __builtin_amdgcn_mfma_f32_16x16x32_bf16(av[m], bv[n], acc[m][n], 0, 0, 0);

        __syncthreads();
        cur ^= 1;
    }
#undef STAGE

    // wave-level triangle/cross flags
    const int  old_by   = 2 * by2 + wr;               // this wave's 128-row old-block
    const bool row_act  = (bx >= old_by);
    const bool col_act  = (bx >  old_by);
    const bool is_cross = (old_by < 32) && (bx >= 32);

    float    cs[4] = {0.f, 0.f, 0.f, 0.f};            // col-side exp sums
    uint32_t s1[4] = {0u, 0u, 0u, 0u};                // col-side top-2
    uint32_t s2[4] = {0u, 0u, 0u, 0u};

    // ---- single fused epilogue pass ----
#pragma unroll
    for (int m = 0; m < 8; m++) {
#pragma unroll
        for (int r = 0; r < 4; r++) {
            int grow = brow + wr * 128 + m * 16 + ((lane >> 4) << 2) + r;
            float rs = 0.f;
            uint32_t t1 = 0u, t2 = 0u;
#pragma unroll
            for (int n = 0; n < 4; n++) {
                int gcol = bcol + wc * 64 + n * 16 + (lane & 15);
                float v  = acc[m][n][r];
                float e  = (grow == gcol) ? 0.f : __expf(v * INV_TAU);
                rs += e;
                cs[n] += e;
                if (is_cross) {
                    int cidx = gcol - HALF_N;
                    ushort h;
                    *(_Float16*)&h = (_Float16)v;
                    uint32_t key = ((uint32_t)(ushort)(h ^ (ushort)((ushort)((short)h >> 15) | 0x8000))) << 16;
                    uint32_t xr = key | (uint32_t)(4095 - cidx);   // row-side: col index
                    uint32_t mn = umin32(t1, xr);
                    t1 = umax32(t1, xr);
                    t2 = umax32(t2, mn);
                    uint32_t xc = key | (uint32_t)(4095 - grow);   // col-side: row index
                    mn = umin32(s1[n], xc);
                    s1[n] = umax32(s1[n], xc);
                    s2[n] = umax32(s2[n], mn);
                    if (cidx == grow && row_act) { pos_sim[grow] = v; pos_sim[gcol] = v; }
                }
            }
            rs += __shfl_xor(rs, 1);
            rs += __shfl_xor(rs, 2);
            rs += __shfl_xor(rs, 4);
            rs += __shfl_xor(rs, 8);
            if (row_act && (lane & 15) == 0) atomicAdd(&rowsum[grow], rs);

            if (is_cross && row_act) {
#pragma unroll
                for (int o = 1; o < 16; o <<= 1) {
                    uint32_t o1 = __shfl_xor(t1, o);
                    uint32_t o2 = __shfl_xor(t2, o);
                    uint32_t nt2 = umax32(umin32(t1, o1), umax32(t2, o2));
                    t1 = umax32(t1, o1);
                    t2 = nt2;
                }
                if ((lane & 15) == 0)
                    partial[((size_t)grow << 6) + (bx - 32) * 2 + wc] = make_uint2(t1, t2);
            }
        }
    }

    // ---- col-side finalize (reduce over lane bits 4,5 = row offsets) ----
    if (col_act) {
#pragma unroll
        for (int n = 0; n < 4; n++) {
            float c = cs[n];
            c += __shfl_xor(c, 16);
            c += __shfl_xor(c, 32);
            uint32_t a1 = s1[n], a2 = s2[n];
            if (is_cross) {
#pragma unroll
                for (int o = 16; o < 64; o <<= 1) {
                    uint32_t o1 = __shfl_xor(a1, o);
                    uint32_t o2 = __shfl_xor(a2, o);
                    uint32_t nt2 = umax32(umin32(a1, o1), umax32(a2, o2));
                    a1 = umax32(a1, o1);
                    a2 = nt2;
                }
            }
            if (lane < 16) {
                int gcol = bcol + wc * 64 + n * 16 + lane;
                atomicAdd(&rowsum[gcol], c);
                if (is_cross)
                    partial[((size_t)gcol << 6) + old_by] = make_uint2(a1, a2);
            }
        }
    }
}

// ---------------- Kernel 2: per-row top-10 + per-row loss --------------
// First-half rows: 64 slots (row side). Second-half rows: 32 slots
// (col side, slot=old_by); lanes 32..63 contribute packed-0 (never wins,
// and slots 32..63 are never read -> no memset needed).
__global__ __launch_bounds__(256) void topk_loss_kernel(const uint2* __restrict__ partial,
                                                        const float* __restrict__ pos_sim,
                                                        const float* __restrict__ rowsum,
                                                        float* __restrict__ contrib)
{
    int i    = blockIdx.x * 4 + (threadIdx.x >> 6);
    int lane = threadIdx.x & 63;

    uint2 p = make_uint2(0u, 0u);
    if (i < HALF_N || lane < 32) p = partial[((size_t)i << 6) + lane];
    uint32_t t1 = p.x, t2 = p.y;

    int posidx = i & (HALF_N - 1);
    float S10 = 0.f; int posflag = 0;
#pragma unroll
    for (int tc = 0; tc < 10; tc++) {
        uint32_t b = umax32(t1, t2);
#pragma unroll
        for (int o = 32; o; o >>= 1)
            b = umax32(b, __shfl_xor(b, o));
        bool w1 = (b == t1);
        bool w2 = (b == t2);
        t1 = w1 ? t2 : t1;
        t2 = (w1 | w2) ? 0u : t2;

        int idx = 4095 - (int)(b & 0xFFFFu);
        S10 += decode_key(b >> 16);
        posflag |= (idx == posidx) ? 1 : 0;
    }

    if (lane == 0) {
        float ps  = pos_sim[i];
        float lse = logf(rowsum[i]);
        float L   = 1.0f + 0.75f * (10 - posflag);
        float sll = INV_TAU * (ps + 0.75f * (S10 - posflag * ps));
        contrib[i] = L * lse - sll;
    }
}

// ---------------- Kernel 3: deterministic final reduce -----------------
__global__ __launch_bounds__(256) void reduce_kernel(const float* __restrict__ contrib,
                                                     float* __restrict__ out)
{
    int t = threadIdx.x;
    float s = 0.f;
    for (int j = t; j < N_TOTAL; j += 256) s += contrib[j];
#pragma unroll
    for (int o = 1; o < 64; o <<= 1) s += __shfl_xor(s, o);
    __shared__ float wsum[4];
    if ((t & 63) == 0) wsum[t >> 6] = s;
    __syncthreads();
    if (t == 0) out[0] = (wsum[0] + wsum[1] + wsum[2] + wsum[3]) * (1.0f / N_TOTAL);
}

extern "C" void kernel_launch(void* const* d_in, const int* in_sizes, int n_in,
                              void* d_out, int out_size, void* d_ws, size_t ws_size,
                              hipStream_t stream)
{
    const float* z1 = (const float*)d_in[0];
    const float* z2 = (const float*)d_in[1];
    float* out = (float*)d_out;

    char* ws = (char*)d_ws;
    ushort* zb      = (ushort*)ws;                     //  8 MB   8192x512 bf16
    float*  rowsum  = (float*)(ws + 8388608);          // 32 KB
    float*  pos_sim = (float*)(ws + 8421376);          // 32 KB
    uint2*  partial = (uint2*)(ws + 8454144);          //  4 MB   8192x64 uint2
    float*  contrib = (float*)(ws + 12648448);         // 32 KB

    norm_kernel<<<N_TOTAL / 4, 256, 0, stream>>>(z1, z2, zb, rowsum);
    gemm_kernel<<<1056, 256, 0, stream>>>(zb, rowsum, partial, pos_sim);
    topk_loss_kernel<<<N_TOTAL / 4, 256, 0, stream>>>(partial, pos_sim, rowsum, contrib);
    reduce_kernel<<<1, 256, 0, stream>>>(contrib, out);
}

// Round 12
// 92.036 us; speedup vs baseline: 1.4455x; 1.1745x over previous
//
#include <hip/hip_runtime.h>
#include <hip/hip_bf16.h>
#include <stdint.h>

#define N_TOTAL 8192
#define HALF_N  4096
#define DIM     512
#define INV_TAU (1.0f/0.07f)

typedef __attribute__((ext_vector_type(4))) int   i32x4;

#define AS1 __attribute__((address_space(1)))
#define AS3 __attribute__((address_space(3)))

__device__ __forceinline__ uint32_t umax32(uint32_t a, uint32_t b) { return a > b ? a : b; }
__device__ __forceinline__ uint32_t umin32(uint32_t a, uint32_t b) { return a < b ? a : b; }

__device__ __forceinline__ float decode_key(uint32_t key)
{
    ushort h = (key & 0x8000u) ? (ushort)(key ^ 0x8000u) : (ushort)(key ^ 0xFFFFu);
    return (float)(*(_Float16*)&h);
}

// ------- Kernel 0: normalize -> int8 quantize (q=rint(127*z~)), inv_qn,
//         and zero rowsum (no separate memset) -------------------------
__global__ __launch_bounds__(256) void norm_kernel(const float* __restrict__ z1,
                                                   const float* __restrict__ z2,
                                                   char* __restrict__ zq,
                                                   float* __restrict__ inv_qn,
                                                   float* __restrict__ rowsum)
{
    if (threadIdx.x < 4) rowsum[blockIdx.x * 4 + threadIdx.x] = 0.f;

    int row  = blockIdx.x * 4 + (threadIdx.x >> 6);
    int lane = threadIdx.x & 63;
    const float* src = (row < HALF_N) ? (z1 + (size_t)row * DIM)
                                      : (z2 + (size_t)(row - HALF_N) * DIM);
    const float4* p = (const float4*)src;
    float4 a = p[lane * 2];
    float4 b = p[lane * 2 + 1];
    float ss = a.x*a.x + a.y*a.y + a.z*a.z + a.w*a.w
             + b.x*b.x + b.y*b.y + b.z*b.z + b.w*b.w;
#pragma unroll
    for (int o = 1; o < 64; o <<= 1) ss += __shfl_xor(ss, o);
    float sc = 127.0f / fmaxf(sqrtf(ss), 1e-12f);

    float v[8] = {a.x*sc, a.y*sc, a.z*sc, a.w*sc, b.x*sc, b.y*sc, b.z*sc, b.w*sc};
    char c8[8];
    int qq = 0;
#pragma unroll
    for (int j = 0; j < 8; j++) {
        int qi = (int)rintf(v[j]);
        qq += qi * qi;
        c8[j] = (char)qi;
    }
#pragma unroll
    for (int o = 1; o < 64; o <<= 1) qq += __shfl_xor(qq, o);
    if (lane == 0) inv_qn[row] = 1.0f / sqrtf(fmaxf((float)qq, 1.0f));

    *(uint2*)(zq + (size_t)row * DIM + lane * 8) = *(const uint2*)c8;
}

// ------- Kernel 1: upper-triangle 128x128 int8 MFMA GEMM --------------
// R7's exact proven structure (2-phase dbuf, 32 KB LDS, 4 waves, 4
// gload_lds/K-step, pre-swizzled source) but i8/BK=64: mfma_i32_16x16x64
// covers 2x K per instruction at the SAME LDS/VGPR/wave budget -> K-steps
// halve 16->8 (barrier drains halve), input bytes halve. sim recovered as
// exact cosine of quantized vectors: v = dot_i32 * inv_qn[r] * inv_qn[c].
__global__ __launch_bounds__(256, 4) void gemm_kernel(const char* __restrict__ zq,
                                                      const float* __restrict__ inv_qn,
                                                      float* __restrict__ rowsum,
                                                      uint2* __restrict__ partial,
                                                      float* __restrict__ pos_sim)
{
    // XCD-aware swizzle: 2080 = 8 * 260, bijective
    int orig = blockIdx.x;
    int bid  = (orig & 7) * 260 + (orig >> 3);

    // triangular decode: bid -> (by, bx), bx >= by, 64-wide upper triangle
    int by = (int)(64.5f - sqrtf(4160.25f - 2.0f * (float)bid));
    int off = 64 * by - (by * (by - 1)) / 2;
    if (off > bid) { --by; off = 64 * by - (by * (by - 1)) / 2; }
    else {
        int offn = 64 * (by + 1) - ((by + 1) * by) / 2;
        if (offn <= bid) { ++by; off = offn; }
    }
    int bx = by + (bid - off);

    const int brow = by * 128;
    const int bcol = bx * 128;

    __shared__ char As[2][128 * 64];   // 8 KB per buffer
    __shared__ char Bs[2][128 * 64];   // 32 KB total (== R7)

    const int t    = threadIdx.x;
    const int w    = t >> 6;
    const int lane = t & 63;
    const int wr   = w >> 1, wc = w & 1;       // 2x2 waves of 64x64

    i32x4 acc[4][4] = {};

    // staging: 16B unit c = row*4 + s; source fetches chunk q = s ^ ((row>>1)&3)
    const int c0 = t, c1 = 256 + t;
    const int r0 = c0 >> 2, r1 = c1 >> 2;
    const int q0 = (c0 & 3) ^ ((r0 >> 1) & 3);
    const int q1 = (c1 & 3) ^ ((r1 >> 1) & 3);
    const size_t gaA0 = (size_t)(brow + r0) * DIM + q0 * 16;   // byte offsets
    const size_t gaA1 = (size_t)(brow + r1) * DIM + q1 * 16;
    const size_t gaB0 = (size_t)(bcol + r0) * DIM + q0 * 16;
    const size_t gaB1 = (size_t)(bcol + r1) * DIM + q1 * 16;
    const int l0 = (w * 64) * 16;
    const int l1 = (256 + w * 64) * 16;

#define STAGE(buf, ko) do {                                                        \
    __builtin_amdgcn_global_load_lds((const AS1 uint32_t*)(zq + gaA0 + (ko)),      \
        (AS3 uint32_t*)((char*)As[buf] + l0), 16, 0, 0);                           \
    __builtin_amdgcn_global_load_lds((const AS1 uint32_t*)(zq + gaA1 + (ko)),      \
        (AS3 uint32_t*)((char*)As[buf] + l1), 16, 0, 0);                           \
    __builtin_amdgcn_global_load_lds((const AS1 uint32_t*)(zq + gaB0 + (ko)),      \
        (AS3 uint32_t*)((char*)Bs[buf] + l0), 16, 0, 0);                           \
    __builtin_amdgcn_global_load_lds((const AS1 uint32_t*)(zq + gaB1 + (ko)),      \
        (AS3 uint32_t*)((char*)Bs[buf] + l1), 16, 0, 0);                           \
} while (0)

    STAGE(0, 0);
    __syncthreads();

    int cur = 0;
    for (int kt = 0; kt < DIM / 64; ++kt) {
        if (kt + 1 < DIM / 64) STAGE(cur ^ 1, (kt + 1) * 64);

        i32x4 av[4], bv[4];
#pragma unroll
        for (int m = 0; m < 4; m++) {
            int ro = wr * 64 + m * 16 + (lane & 15);
            int s  = (lane >> 4) ^ ((ro >> 1) & 3);
            av[m] = *(const i32x4*)(As[cur] + ro * 64 + s * 16);
        }
#pragma unroll
        for (int n = 0; n < 4; n++) {
            int ro = wc * 64 + n * 16 + (lane & 15);
            int s  = (lane >> 4) ^ ((ro >> 1) & 3);
            bv[n] = *(const i32x4*)(Bs[cur] + ro * 64 + s * 16);
        }
#pragma unroll
        for (int m = 0; m < 4; m++)
#pragma unroll
            for (int n = 0; n < 4; n++)
                acc[m][n] = __builtin_amdgcn_mfma_i32_16x16x64_i8(av[m], bv[n], acc[m][n], 0, 0, 0);

        __syncthreads();
        cur ^= 1;
    }
#undef STAGE

    const bool is_cross = (brow < HALF_N) && (bcol >= HALF_N);
    const bool off_diag = (bx != by);

    float invc[4];
#pragma unroll
    for (int n = 0; n < 4; n++)
        invc[n] = inv_qn[bcol + wc * 64 + n * 16 + (lane & 15)];

    float    cs[4] = {0.f, 0.f, 0.f, 0.f};          // col-side exp sums
    uint32_t s1[4] = {0u, 0u, 0u, 0u};              // col-side top-2
    uint32_t s2[4] = {0u, 0u, 0u, 0u};

    // ---- single fused epilogue pass ----
#pragma unroll
    for (int m = 0; m < 4; m++) {
#pragma unroll
        for (int r = 0; r < 4; r++) {
            int grow = brow + wr * 64 + m * 16 + ((lane >> 4) << 2) + r;
            float invr = inv_qn[grow];
            float rs = 0.f;
            uint32_t t1 = 0u, t2 = 0u;
#pragma unroll
            for (int n = 0; n < 4; n++) {
                int gcol = bcol + wc * 64 + n * 16 + (lane & 15);
                float v  = (float)acc[m][n][r] * (invr * invc[n]);
                float e  = (grow == gcol) ? 0.f : __expf(v * INV_TAU);
                rs += e;
                cs[n] += e;
                if (is_cross) {
                    int cidx = gcol - HALF_N;
                    ushort h;
                    *(_Float16*)&h = (_Float16)v;
                    uint32_t key = ((uint32_t)(ushort)(h ^ (ushort)((ushort)((short)h >> 15) | 0x8000))) << 16;
                    uint32_t xr = key | (uint32_t)(4095 - cidx);   // row-side: col index
                    uint32_t mn = umin32(t1, xr);
                    t1 = umax32(t1, xr);
                    t2 = umax32(t2, mn);
                    uint32_t xc = key | (uint32_t)(4095 - grow);   // col-side: row index
                    mn = umin32(s1[n], xc);
                    s1[n] = umax32(s1[n], xc);
                    s2[n] = umax32(s2[n], mn);
                    if (cidx == grow) { pos_sim[grow] = v; pos_sim[gcol] = v; }
                }
            }
            rs += __shfl_xor(rs, 1);
            rs += __shfl_xor(rs, 2);
            rs += __shfl_xor(rs, 4);
            rs += __shfl_xor(rs, 8);
            if ((lane & 15) == 0) atomicAdd(&rowsum[grow], rs);

            if (is_cross) {
#pragma unroll
                for (int o = 1; o < 16; o <<= 1) {
                    uint32_t o1 = __shfl_xor(t1, o);
                    uint32_t o2 = __shfl_xor(t2, o);
                    uint32_t nt2 = umax32(umin32(t1, o1), umax32(t2, o2));
                    t1 = umax32(t1, o1);
                    t2 = nt2;
                }
                if ((lane & 15) == 0)
                    partial[((size_t)grow << 6) + (bx - 32) * 2 + wc] = make_uint2(t1, t2);
            }
        }
    }

    // ---- col-side finalize (reduce over lane bits 4,5 = row groups) ----
    if (off_diag) {
#pragma unroll
        for (int n = 0; n < 4; n++) {
            float c = cs[n];
            c += __shfl_xor(c, 16);
            c += __shfl_xor(c, 32);
            uint32_t a1 = s1[n], a2 = s2[n];
            if (is_cross) {
#pragma unroll
                for (int o = 16; o < 64; o <<= 1) {
                    uint32_t o1 = __shfl_xor(a1, o);
                    uint32_t o2 = __shfl_xor(a2, o);
                    uint32_t nt2 = umax32(umin32(a1, o1), umax32(a2, o2));
                    a1 = umax32(a1, o1);
                    a2 = nt2;
                }
            }
            if (lane < 16) {
                int gcol = bcol + wc * 64 + n * 16 + lane;
                atomicAdd(&rowsum[gcol], c);
                if (is_cross)
                    partial[((size_t)gcol << 6) + by * 2 + wr] = make_uint2(a1, a2);
            }
        }
    }
}

// ------- Kernel 2: per-row top-10 + per-row loss (64 full slots) -------
__global__ __launch_bounds__(256) void topk_loss_kernel(const uint2* __restrict__ partial,
                                                        const float* __restrict__ pos_sim,
                                                        const float* __restrict__ rowsum,
                                                        float* __restrict__ contrib)
{
    int i    = blockIdx.x * 4 + (threadIdx.x >> 6);
    int lane = threadIdx.x & 63;

    uint2 p = partial[((size_t)i << 6) + lane];
    uint32_t t1 = p.x, t2 = p.y;

    int posidx = i & (HALF_N - 1);
    float S10 = 0.f; int posflag = 0;
#pragma unroll
    for (int tc = 0; tc < 10; tc++) {
        uint32_t b = umax32(t1, t2);
#pragma unroll
        for (int o = 32; o; o >>= 1)
            b = umax32(b, __shfl_xor(b, o));
        bool w1 = (b == t1);
        bool w2 = (b == t2);
        t1 = w1 ? t2 : t1;
        t2 = (w1 | w2) ? 0u : t2;

        int idx = 4095 - (int)(b & 0xFFFFu);
        S10 += decode_key(b >> 16);
        posflag |= (idx == posidx) ? 1 : 0;
    }

    if (lane == 0) {
        float ps  = pos_sim[i];
        float lse = logf(rowsum[i]);
        float L   = 1.0f + 0.75f * (10 - posflag);
        float sll = INV_TAU * (ps + 0.75f * (S10 - posflag * ps));
        contrib[i] = L * lse - sll;
    }
}

// ------- Kernel 3: deterministic final reduce --------------------------
__global__ __launch_bounds__(256) void reduce_kernel(const float* __restrict__ contrib,
                                                     float* __restrict__ out)
{
    int t = threadIdx.x;
    float s = 0.f;
    for (int j = t; j < N_TOTAL; j += 256) s += contrib[j];
#pragma unroll
    for (int o = 1; o < 64; o <<= 1) s += __shfl_xor(s, o);
    __shared__ float wsum[4];
    if ((t & 63) == 0) wsum[t >> 6] = s;
    __syncthreads();
    if (t == 0) out[0] = (wsum[0] + wsum[1] + wsum[2] + wsum[3]) * (1.0f / N_TOTAL);
}

extern "C" void kernel_launch(void* const* d_in, const int* in_sizes, int n_in,
                              void* d_out, int out_size, void* d_ws, size_t ws_size,
                              hipStream_t stream)
{
    const float* z1 = (const float*)d_in[0];
    const float* z2 = (const float*)d_in[1];
    float* out = (float*)d_out;

    char* ws = (char*)d_ws;
    char*   zq      = ws;                              //  4 MB   8192x512 int8
    float*  rowsum  = (float*)(ws + 4194304);          // 32 KB
    float*  pos_sim = (float*)(ws + 4227072);          // 32 KB
    float*  inv_qn  = (float*)(ws + 4259840);          // 32 KB
    uint2*  partial = (uint2*)(ws + 4292608);          //  4 MB   8192x64 uint2
    float*  contrib = (float*)(ws + 8486912);          // 32 KB

    norm_kernel<<<N_TOTAL / 4, 256, 0, stream>>>(z1, z2, zq, inv_qn, rowsum);
    gemm_kernel<<<2080, 256, 0, stream>>>(zq, inv_qn, rowsum, partial, pos_sim);
    topk_loss_kernel<<<N_TOTAL / 4, 256, 0, stream>>>(partial, pos_sim, rowsum, contrib);
    reduce_kernel<<<1, 256, 0, stream>>>(contrib, out);
}